// Round 15
// baseline (579.157 us; speedup 1.0000x reference)
//
#include <hip/hip_runtime.h>
#include <math.h>

#define N_NODES 50000
#define N_EDGES 500000
#define D 128
#define CAT 384

typedef __bf16 v8bf __attribute__((ext_vector_type(8)));
typedef __bf16 v2bf __attribute__((ext_vector_type(2)));
typedef float v4f __attribute__((ext_vector_type(4)));

// ---------------------------------------------------------------------------
// Fast transcendentals on the v_exp_f32 / v_rcp_f32 pipes.
__device__ __forceinline__ float erf_fast(float x) {
    float ax = fabsf(x);
    float t = __builtin_amdgcn_rcpf(fmaf(0.3275911f, ax, 1.0f));
    float p = fmaf(1.061405429f, t, -1.453152027f);
    p = fmaf(p, t, 1.421413741f);
    p = fmaf(p, t, -0.284496736f);
    p = fmaf(p, t, 0.254829592f);
    p = p * t;
    float e = __expf(-ax * ax);
    float r = 1.0f - p * e;
    return copysignf(r, x);
}

__device__ __forceinline__ float gelu_fast(float x) {
    return 0.5f * x * (1.0f + erf_fast(x * 0.70710678118654752440f));
}

__device__ __forceinline__ float sigmoid_fast(float x) {
    float e = __expf(-x);
    return __builtin_amdgcn_rcpf(1.0f + e);
}

__device__ __forceinline__ float tanh_fast(float x) {
    float e = __expf(2.0f * x);
    return 1.0f - 2.0f * __builtin_amdgcn_rcpf(e + 1.0f);
}

__device__ __forceinline__ v8bf cvt8(const float* __restrict__ p) {
    float4 f0 = *(const float4*)p;
    float4 f1 = *(const float4*)(p + 4);
    v8bf r;
    r[0] = (__bf16)f0.x; r[1] = (__bf16)f0.y; r[2] = (__bf16)f0.z; r[3] = (__bf16)f0.w;
    r[4] = (__bf16)f1.x; r[5] = (__bf16)f1.y; r[6] = (__bf16)f1.z; r[7] = (__bf16)f1.w;
    return r;
}

// ---------------------------------------------------------------------------
__global__ __launch_bounds__(256) void k_zero(int* __restrict__ counts) {
    int i = blockIdx.x * 256 + threadIdx.x;
    if (i < N_NODES) counts[i] = 0;
}

// ---------------------------------------------------------------------------
// Fused pre-pass: [0,712) weight cvt | [712,744) relpart | [744,...) histogram.
__global__ __launch_bounds__(256) void k_pre(const float* __restrict__ msgW,
                                             const float* __restrict__ W1,
                                             const float* __restrict__ W2,
                                             const float* __restrict__ wih,
                                             const float* __restrict__ whh,
                                             __bf16* __restrict__ WB,
                                             const float* __restrict__ rel_emb,
                                             const float* __restrict__ msg_b,
                                             __bf16* __restrict__ RPB,
                                             const int* __restrict__ ei,
                                             int* __restrict__ counts) {
    int bid = blockIdx.x;
    int t = threadIdx.x;
    if (bid < 712) {
        int i = bid * 256 + t;
        float v;
        if (i < 32768) {
            int j = i >> 7, k = i & 127;
            v = (j < 128) ? msgW[j * CAT + k] : msgW[(j - 128) * CAT + 128 + k];
        } else if (i < 65536) {
            int ii = i - 32768; int j = ii >> 7, k = ii & 127;
            v = (j < 128) ? W1[j * CAT + k] : W1[(j - 128) * CAT + 128 + k];
        } else if (i < 81920) {
            int ii = i - 65536; int j = ii >> 7, k = ii & 127;
            v = W1[j * CAT + 256 + k];
        } else if (i < 83968) {
            v = W2[i - 81920];
        } else if (i < 133120) {
            v = wih[i - 83968];
        } else {
            v = whh[i - 133120];
        }
        WB[i] = (__bf16)v;
    } else if (bid < 744) {
        int r = (bid - 712) * 2 + (t >> 7);
        int j = t & 127;
        const float* er = rel_emb + r * D;
        const float* wr = msgW + j * CAT + 2 * D;
        float acc = msg_b[j];
        #pragma unroll 8
        for (int k = 0; k < D; ++k) acc += er[k] * wr[k];
        RPB[r * D + j] = (__bf16)acc;
    } else {
        int e = (bid - 744) * 256 + t;
        if (e < N_EDGES) atomicAdd(&counts[ei[N_EDGES + e]], 1);
    }
}

// ---------------------------------------------------------------------------
// MFMA node projection (fp32 input), output-col remap j = half*128 + 8c + jt.
__global__ __launch_bounds__(256) void k_proj2_f32(const float* __restrict__ in,
                                                   const __bf16* __restrict__ wb,
                                                   __bf16* __restrict__ out) {
    int t = threadIdx.x;
    int lane = t & 63, wid = t >> 6;
    int g = lane >> 4, c = lane & 15;
    int nbase = blockIdx.x * 64 + wid * 16;

    int nrow = min(nbase + c, N_NODES - 1);
    const float* ir = in + (size_t)nrow * D + g * 8;
    v8bf afrag[4];
    #pragma unroll
    for (int kc = 0; kc < 4; ++kc) afrag[kc] = cvt8(ir + kc * 32);

    #pragma unroll
    for (int half = 0; half < 2; ++half) {
        v4f acc[8];
        #pragma unroll 2
        for (int jt = 0; jt < 8; ++jt) {
            const __bf16* wr = wb + (size_t)(half * 128 + 8 * c + jt) * 128 + g * 8;
            v4f a4 = (v4f){0.f, 0.f, 0.f, 0.f};
            #pragma unroll
            for (int kc = 0; kc < 4; ++kc)
                a4 = __builtin_amdgcn_mfma_f32_16x16x32_bf16(afrag[kc], *(const v8bf*)(wr + kc * 32), a4, 0, 0, 0);
            acc[jt] = a4;
        }
        #pragma unroll
        for (int r = 0; r < 4; ++r) {
            int node = nbase + g * 4 + r;
            v8bf o;
            #pragma unroll
            for (int jt = 0; jt < 8; ++jt) o[jt] = (__bf16)acc[jt][r];
            if (node < N_NODES)
                *(v8bf*)(out + (size_t)node * 256 + half * 128 + 8 * c) = o;
        }
    }
}

// ---------------------------------------------------------------------------
// Single-block scan, 1024 threads.
__global__ __launch_bounds__(1024) void k_scan(const int* __restrict__ counts,
                                               int* __restrict__ offsets,
                                               int* __restrict__ cursor) {
    __shared__ int part[1024];
    int t = threadIdx.x;
    const int CH = 49;                         // 1024*49 = 50176 >= 50000
    int lo = t * CH, hi = min(lo + CH, N_NODES);
    int s = 0;
    for (int i = lo; i < hi; ++i) s += counts[i];
    part[t] = s;
    __syncthreads();
    for (int d = 1; d < 1024; d <<= 1) {
        int v = (t >= d) ? part[t - d] : 0;
        __syncthreads();
        part[t] += v;
        __syncthreads();
    }
    int run = (t == 0) ? 0 : part[t - 1];
    for (int i = lo; i < hi; ++i) {
        offsets[i] = run;
        cursor[i] = run;
        run += counts[i];
    }
    if (t == 1023) offsets[N_NODES] = run;
}

__global__ __launch_bounds__(256) void k_scatter(const int* __restrict__ ei,
                                                 int* __restrict__ cursor,
                                                 int* __restrict__ elist) {
    int e = blockIdx.x * 256 + threadIdx.x;
    if (e < N_EDGES) {
        int slot = atomicAdd(&cursor[ei[N_EDGES + e]], 1);
        elist[slot] = e;
    }
}

// ---------------------------------------------------------------------------
// Aggregation, atomic-free; 4-deep index prefetch + 2-deep row-data prefetch.
__global__ __launch_bounds__(256) void k_agg(const __bf16* __restrict__ PSTB,
                                             const __bf16* __restrict__ RPB,
                                             const int* __restrict__ ei,
                                             const int* __restrict__ lab,
                                             const int* __restrict__ offsets,
                                             const int* __restrict__ elist,
                                             __bf16* __restrict__ agg) {
    int t = threadIdx.x;
    int wid = t >> 6, lane = t & 63;
    int n = blockIdx.x * 4 + wid;
    if (n >= N_NODES) return;
    int beg = offsets[n], end = offsets[n + 1];

    v2bf ptv = *(const v2bf*)(PSTB + (size_t)n * 256 + 128 + lane * 2);
    float pt0 = (float)ptv[0], pt1 = (float)ptv[1];

    float a0 = 0.f, a1 = 0.f;
    if (beg < end) {
        int mx = end - 1;
        int eA = elist[beg];
        int eB = elist[min(beg + 1, mx)];
        int e2 = elist[min(beg + 2, mx)];
        int e3 = elist[min(beg + 3, mx)];
        int sA = ei[eA], lA = lab[eA];
        int sB = ei[eB], lB = lab[eB];
        int s2 = ei[e2], l2 = lab[e2];
        int s3 = ei[e3], l3 = lab[e3];
        v2bf psA = *(const v2bf*)(PSTB + (size_t)sA * 256 + lane * 2);
        v2bf rpA = *(const v2bf*)(RPB + (size_t)lA * D + lane * 2);
        v2bf psB = *(const v2bf*)(PSTB + (size_t)sB * 256 + lane * 2);
        v2bf rpB = *(const v2bf*)(RPB + (size_t)lB * D + lane * 2);

        for (int idx = beg; idx < end; idx += 2) {
            v2bf cpsA = psA, crpA = rpA, cpsB = psB, crpB = rpB;
            bool hasB = (idx + 1 < end);
            psA = *(const v2bf*)(PSTB + (size_t)s2 * 256 + lane * 2);
            rpA = *(const v2bf*)(RPB + (size_t)l2 * D + lane * 2);
            psB = *(const v2bf*)(PSTB + (size_t)s3 * 256 + lane * 2);
            rpB = *(const v2bf*)(RPB + (size_t)l3 * D + lane * 2);
            int e4 = elist[min(idx + 4, mx)];
            int e5 = elist[min(idx + 5, mx)];
            s2 = ei[e4]; l2 = lab[e4];
            s3 = ei[e5]; l3 = lab[e5];
            a0 += gelu_fast((float)cpsA[0] + pt0 + (float)crpA[0]);
            a1 += gelu_fast((float)cpsA[1] + pt1 + (float)crpA[1]);
            if (hasB) {
                a0 += gelu_fast((float)cpsB[0] + pt0 + (float)crpB[0]);
                a1 += gelu_fast((float)cpsB[1] + pt1 + (float)crpB[1]);
            }
        }
    }
    v2bf o; o[0] = (__bf16)a0; o[1] = (__bf16)a1;
    *(v2bf*)(agg + (size_t)n * D + lane * 2) = o;
}

// ---------------------------------------------------------------------------
// FUSED GRU + projection (r14 structure unchanged).
__global__ __launch_bounds__(256) void k_gru_fused(const __bf16* __restrict__ agg,
                                                   const float* __restrict__ nf,
                                                   const __bf16* __restrict__ WIH,
                                                   const __bf16* __restrict__ WHH,
                                                   const float* __restrict__ b_ih,
                                                   const float* __restrict__ b_hh,
                                                   const __bf16* __restrict__ WQ1,
                                                   __bf16* __restrict__ QSTB) {
    __shared__ __align__(16) __bf16 nfu_s[64][128];   // 16 KB
    int t = threadIdx.x;
    int lane = t & 63, wid = t >> 6;
    int g = lane >> 4, c = lane & 15;
    int nbase = blockIdx.x * 64 + wid * 16;

    int nrow = min(nbase + c, N_NODES - 1);
    const __bf16* ar = agg + (size_t)nrow * D + g * 8;
    const float* hr = nf + (size_t)nrow * D + g * 8;
    v8bf afrag[4], hfrag[4];
    #pragma unroll
    for (int kc = 0; kc < 4; ++kc) {
        afrag[kc] = *(const v8bf*)(ar + kc * 32);
        hfrag[kc] = cvt8(hr + kc * 32);
    }

    float h8[4][8];
    #pragma unroll
    for (int r = 0; r < 4; ++r) {
        int node = min(nbase + g * 4 + r, N_NODES - 1);
        float4 f0 = *(const float4*)(nf + (size_t)node * D + 8 * c);
        float4 f1 = *(const float4*)(nf + (size_t)node * D + 8 * c + 4);
        h8[r][0]=f0.x; h8[r][1]=f0.y; h8[r][2]=f0.z; h8[r][3]=f0.w;
        h8[r][4]=f1.x; h8[r][5]=f1.y; h8[r][6]=f1.z; h8[r][7]=f1.w;
    }

    v8bf o[4];
    for (int jt = 0; jt < 8; ++jt) {
        int j = 8 * c + jt;
        const __bf16* wir = WIH + (size_t)j * 128 + g * 8;
        const __bf16* whr = WHH + (size_t)j * 128 + g * 8;
        v4f a_ir = (v4f){0.f,0.f,0.f,0.f}, a_iz = a_ir, a_in = a_ir;
        v4f a_hr = a_ir, a_hz = a_ir, a_hn = a_ir;
        #pragma unroll
        for (int kc = 0; kc < 4; ++kc) {
            a_ir = __builtin_amdgcn_mfma_f32_16x16x32_bf16(afrag[kc], *(const v8bf*)(wir + kc * 32), a_ir, 0, 0, 0);
            a_iz = __builtin_amdgcn_mfma_f32_16x16x32_bf16(afrag[kc], *(const v8bf*)(wir + 128 * 128 + kc * 32), a_iz, 0, 0, 0);
            a_in = __builtin_amdgcn_mfma_f32_16x16x32_bf16(afrag[kc], *(const v8bf*)(wir + 256 * 128 + kc * 32), a_in, 0, 0, 0);
            a_hr = __builtin_amdgcn_mfma_f32_16x16x32_bf16(hfrag[kc], *(const v8bf*)(whr + kc * 32), a_hr, 0, 0, 0);
            a_hz = __builtin_amdgcn_mfma_f32_16x16x32_bf16(hfrag[kc], *(const v8bf*)(whr + 128 * 128 + kc * 32), a_hz, 0, 0, 0);
            a_hn = __builtin_amdgcn_mfma_f32_16x16x32_bf16(hfrag[kc], *(const v8bf*)(whr + 256 * 128 + kc * 32), a_hn, 0, 0, 0);
        }
        float bir = b_ih[j], biz = b_ih[128 + j], bin = b_ih[256 + j];
        float bhr = b_hh[j], bhz = b_hh[128 + j], bhn = b_hh[256 + j];
        #pragma unroll
        for (int r = 0; r < 4; ++r) {
            float irv = a_ir[r] + bir, hrv = a_hr[r] + bhr;
            float izv = a_iz[r] + biz, hzv = a_hz[r] + bhz;
            float inv = a_in[r] + bin, hnv = a_hn[r] + bhn;
            float rg = sigmoid_fast(irv + hrv);
            float zg = sigmoid_fast(izv + hzv);
            float ng = tanh_fast(inv + rg * hnv);
            o[r][jt] = (__bf16)((1.f - zg) * ng + zg * h8[r][jt]);
        }
    }
    #pragma unroll
    for (int r = 0; r < 4; ++r) {
        int lr = wid * 16 + g * 4 + r;
        *(v8bf*)&nfu_s[lr][8 * (c ^ (lr & 7))] = o[r];
    }

    int lr2 = wid * 16 + c;
    v8bf pfrag[4];
    #pragma unroll
    for (int kc = 0; kc < 4; ++kc)
        pfrag[kc] = *(const v8bf*)&nfu_s[lr2][8 * ((g + 4 * kc) ^ (c & 7))];

    #pragma unroll
    for (int half = 0; half < 2; ++half) {
        v4f acc[8];
        #pragma unroll 2
        for (int jt = 0; jt < 8; ++jt) {
            const __bf16* wr = WQ1 + (size_t)(half * 128 + 8 * c + jt) * 128 + g * 8;
            v4f a4 = (v4f){0.f, 0.f, 0.f, 0.f};
            #pragma unroll
            for (int kc = 0; kc < 4; ++kc)
                a4 = __builtin_amdgcn_mfma_f32_16x16x32_bf16(pfrag[kc], *(const v8bf*)(wr + kc * 32), a4, 0, 0, 0);
            acc[jt] = a4;
        }
        #pragma unroll
        for (int r = 0; r < 4; ++r) {
            int node = nbase + g * 4 + r;
            v8bf oo;
            #pragma unroll
            for (int jt = 0; jt < 8; ++jt) oo[jt] = (__bf16)acc[jt][r];
            if (node < N_NODES)
                *(v8bf*)(QSTB + (size_t)node * 256 + half * 128 + 8 * c) = oo;
        }
    }
}

// ---------------------------------------------------------------------------
// MFMA classifier v9: 512-thread / 8-wave persistent blocks (128-edge tiles).
// LDS 64KB -> 2 blocks/CU -> 16 waves/CU (+33% TLP vs the 256-thread version).
// Same r14 software pipeline: ef[T] issued iter T-1 BEFORE gathers[T];
// gathers consumed at epilogue (full iteration in flight); idx[T+1] staged.
__global__ __launch_bounds__(512) void k_cls_mfma(const float* __restrict__ ef,
                                                  const __bf16* __restrict__ QSTB,
                                                  const __bf16* __restrict__ V3,
                                                  const float* __restrict__ b1,
                                                  const __bf16* __restrict__ W2B,
                                                  const float* __restrict__ b2,
                                                  const int* __restrict__ ei,
                                                  float* __restrict__ out) {
    __shared__ __align__(16) __bf16 v3_s[128][128];   // 32 KB
    __shared__ __align__(16) __bf16 hc_s[128][128];   // 32 KB (8 waves x 16 rows)
    int t = threadIdx.x;
    int lane = t & 63, w = t >> 6;              // w in 0..7
    int g = lane >> 4, c = lane & 15;
    const int ntile = (N_EDGES + 127) / 128;    // 128 edges per tile
    const int stride = gridDim.x;

    int tile = blockIdx.x;

    // hoisted invariants
    v8bf w2frag[4];
    #pragma unroll
    for (int kc = 0; kc < 4; ++kc)
        w2frag[kc] = *(const v8bf*)(W2B + c * 128 + (g + 4 * kc) * 8);
    float4 b1a = *(const float4*)(b1 + 8 * c);
    float4 b1b = *(const float4*)(b1 + 8 * c + 4);
    float b1r[8] = {b1a.x, b1a.y, b1a.z, b1a.w, b1b.x, b1b.y, b1b.z, b1b.w};
    float b2c = b2[c];

    // prologue: ef[tile] + idx[tile]
    float4 efraw[8];
    int sr[4], tr[4];
    {
        int e_base = tile * 128 + w * 16;
        int er = min(e_base + c, N_EDGES - 1);
        const float* efr = ef + (size_t)er * D + g * 8;
        #pragma unroll
        for (int kc = 0; kc < 4; ++kc) {
            efraw[2 * kc]     = *(const float4*)(efr + kc * 32);
            efraw[2 * kc + 1] = *(const float4*)(efr + kc * 32 + 4);
        }
        #pragma unroll
        for (int r = 0; r < 4; ++r) {
            int e = min(e_base + g * 4 + r, N_EDGES - 1);
            sr[r] = ei[e];
            tr[r] = ei[N_EDGES + e];
        }
    }

    // stage V3 into LDS, chunk-swizzled (once per block; 512 threads x 4)
    #pragma unroll
    for (int i = 0; i < 4; ++i) {
        int idx = t * 4 + i;                    // 0..2047 16B-chunks
        int row = idx >> 4, ch = idx & 15;
        v8bf v = *(const v8bf*)(V3 + row * 128 + ch * 8);
        *(v8bf*)&v3_s[row][8 * (ch ^ ((row >> 3) & 7))] = v;
    }
    __syncthreads();

    // prologue: issue gathers[tile]; load idx[tile+stride]
    v8bf qs[4], qt[4];
    #pragma unroll
    for (int r = 0; r < 4; ++r) {
        qs[r] = *(const v8bf*)(QSTB + (size_t)sr[r] * 256 + 8 * c);
        qt[r] = *(const v8bf*)(QSTB + (size_t)tr[r] * 256 + 128 + 8 * c);
    }
    int srn[4], trn[4];
    if (tile + stride < ntile) {
        int nb = (tile + stride) * 128 + w * 16;
        #pragma unroll
        for (int r = 0; r < 4; ++r) {
            int e = min(nb + g * 4 + r, N_EDGES - 1);
            srn[r] = ei[e];
            trn[r] = ei[N_EDGES + e];
        }
    }

    while (tile < ntile) {
        int nxt = tile + stride;
        int e_base = tile * 128 + w * 16;

        // (1) A-fragments from efraw (older than gathers -> no drain)
        v8bf afrag[4];
        #pragma unroll
        for (int kc = 0; kc < 4; ++kc) {
            v8bf a;
            float4 f0 = efraw[2 * kc], f1 = efraw[2 * kc + 1];
            a[0] = (__bf16)f0.x; a[1] = (__bf16)f0.y; a[2] = (__bf16)f0.z; a[3] = (__bf16)f0.w;
            a[4] = (__bf16)f1.x; a[5] = (__bf16)f1.y; a[6] = (__bf16)f1.z; a[7] = (__bf16)f1.w;
            afrag[kc] = a;
        }

        // (2) issue ef[T+1]
        if (nxt < ntile) {
            int nb = nxt * 128 + w * 16;
            int er = min(nb + c, N_EDGES - 1);
            const float* efr = ef + (size_t)er * D + g * 8;
            #pragma unroll
            for (int kc = 0; kc < 4; ++kc) {
                efraw[2 * kc]     = *(const float4*)(efr + kc * 32);
                efraw[2 * kc + 1] = *(const float4*)(efr + kc * 32 + 4);
            }
        }

        // (3) issue gathers[T+1]
        v8bf qsn[4], qtn[4];
        if (nxt < ntile) {
            #pragma unroll
            for (int r = 0; r < 4; ++r) {
                qsn[r] = *(const v8bf*)(QSTB + (size_t)srn[r] * 256 + 8 * c);
                qtn[r] = *(const v8bf*)(QSTB + (size_t)trn[r] * 256 + 128 + 8 * c);
            }
        }

        // (4) issue idx[T+2]
        if (nxt + stride < ntile) {
            int nb = (nxt + stride) * 128 + w * 16;
            #pragma unroll
            for (int r = 0; r < 4; ++r) {
                int e = min(nb + g * 4 + r, N_EDGES - 1);
                srn[r] = ei[e];
                trn[r] = ei[N_EDGES + e];
            }
        }

        // (5) GEMM1 from LDS (lgkmcnt only)
        v4f acc[8];
        #pragma unroll
        for (int jt = 0; jt < 8; ++jt) {
            int row = 8 * c + jt;
            v4f a4 = (v4f){0.f, 0.f, 0.f, 0.f};
            #pragma unroll
            for (int kc = 0; kc < 4; ++kc) {
                v8bf bb = *(const v8bf*)&v3_s[row][8 * ((g + 4 * kc) ^ (c & 7))];
                a4 = __builtin_amdgcn_mfma_f32_16x16x32_bf16(afrag[kc], bb, a4, 0, 0, 0);
            }
            acc[jt] = a4;
        }

        // (6) epilogue with gathers[T]
        #pragma unroll
        for (int r = 0; r < 4; ++r) {
            int el = w * 16 + g * 4 + r;
            v8bf o;
            #pragma unroll
            for (int jt = 0; jt < 8; ++jt) {
                float v = acc[jt][r] + (float)qs[r][jt] + (float)qt[r][jt] + b1r[jt];
                o[jt] = (__bf16)gelu_fast(v);
            }
            *(v8bf*)&hc_s[el][8 * (c ^ (el & 7))] = o;
        }

        // (7) GEMM2 + store (hc round-trip wave-local: rows [16w,16w+16))
        v4f acc2 = (v4f){0.f, 0.f, 0.f, 0.f};
        int arow = w * 16 + c;
        #pragma unroll
        for (int kc = 0; kc < 4; ++kc) {
            int ch = g + 4 * kc;
            v8bf aa = *(const v8bf*)&hc_s[arow][8 * (ch ^ (c & 7))];
            acc2 = __builtin_amdgcn_mfma_f32_16x16x32_bf16(aa, w2frag[kc], acc2, 0, 0, 0);
        }
        #pragma unroll
        for (int r = 0; r < 4; ++r) {
            int e = e_base + g * 4 + r;
            if (e < N_EDGES) out[(size_t)e * 16 + c] = acc2[r] + b2c;
        }

        // (8) rotate
        #pragma unroll
        for (int r = 0; r < 4; ++r) { qs[r] = qsn[r]; qt[r] = qtn[r]; }
        tile = nxt;
    }
}

// ---------------------------------------------------------------------------
extern "C" void kernel_launch(void* const* d_in, const int* in_sizes, int n_in,
                              void* d_out, int out_size, void* d_ws, size_t ws_size,
                              hipStream_t stream) {
    const float* nf   = (const float*)d_in[0];
    const float* ef   = (const float*)d_in[1];
    const int*   ei   = (const int*)d_in[2];
    const int*   lab  = (const int*)d_in[3];
    const float* rel  = (const float*)d_in[4];
    const float* msgW = (const float*)d_in[5];
    const float* msgb = (const float*)d_in[6];
    const float* wih  = (const float*)d_in[7];
    const float* whh  = (const float*)d_in[8];
    const float* bih  = (const float*)d_in[9];
    const float* bhh  = (const float*)d_in[10];
    const float* W1   = (const float*)d_in[11];
    const float* b1   = (const float*)d_in[12];
    const float* W2   = (const float*)d_in[13];
    const float* b2   = (const float*)d_in[14];
    float* out = (float*)d_out;

    char* ws = (char*)d_ws;
    __bf16* WB      = (__bf16*)(ws);                  // 364.5 KB
    __bf16* RPB     = (__bf16*)(ws + 524288);         // 16 KB
    int*    offsets = (int*)(ws + 1048576);           // 200 KB (N+1)
    int*    counts  = (int*)(ws + 1310720);           // 200 KB
    int*    cursor  = (int*)(ws + 1572864);           // 200 KB
    int*    elist   = (int*)(ws + 1835008);           // 2 MB
    __bf16* PSTB    = (__bf16*)(ws + 4194304);        // 25.6 MB
    __bf16* AGG     = (__bf16*)(ws + 33554432);       // 12.8 MB
    __bf16* QSTB    = PSTB;                           // reuse after k_agg

    __bf16* WP1 = WB;
    __bf16* WQ1 = WB + 32768;
    __bf16* V3  = WB + 65536;
    __bf16* W2B = WB + 81920;
    __bf16* WIH = WB + 83968;
    __bf16* WHH = WB + 133120;

    int nblk = (N_NODES + 63) / 64;
    int eblk = (N_EDGES + 255) / 256;

    k_zero<<<(N_NODES + 255) / 256, 256, 0, stream>>>(counts);
    k_pre<<<744 + eblk, 256, 0, stream>>>(msgW, W1, W2, wih, whh, WB,
                                          rel, msgb, RPB, ei, counts);
    k_proj2_f32<<<nblk, 256, 0, stream>>>(nf, WP1, PSTB);
    k_scan<<<1, 1024, 0, stream>>>(counts, offsets, cursor);
    k_scatter<<<eblk, 256, 0, stream>>>(ei, cursor, elist);
    k_agg<<<(N_NODES + 3) / 4, 256, 0, stream>>>(PSTB, RPB, ei, lab, offsets, elist, AGG);
    k_gru_fused<<<nblk, 256, 0, stream>>>(AGG, nf, WIH, WHH, bih, bhh, WQ1, QSTB);
    k_cls_mfma<<<512, 512, 0, stream>>>(ef, QSTB, V3, b1, W2B, b2, ei, out);
}

// Round 16
// 523.949 us; speedup vs baseline: 1.1054x; 1.1054x over previous
//
#include <hip/hip_runtime.h>
#include <math.h>

#define N_NODES 50000
#define N_EDGES 500000
#define D 128
#define CAT 384

typedef __bf16 v8bf __attribute__((ext_vector_type(8)));
typedef __bf16 v2bf __attribute__((ext_vector_type(2)));
typedef float v4f __attribute__((ext_vector_type(4)));

// ---------------------------------------------------------------------------
// Fast transcendentals on the v_exp_f32 / v_rcp_f32 pipes.
__device__ __forceinline__ float erf_fast(float x) {
    float ax = fabsf(x);
    float t = __builtin_amdgcn_rcpf(fmaf(0.3275911f, ax, 1.0f));
    float p = fmaf(1.061405429f, t, -1.453152027f);
    p = fmaf(p, t, 1.421413741f);
    p = fmaf(p, t, -0.284496736f);
    p = fmaf(p, t, 0.254829592f);
    p = p * t;
    float e = __expf(-ax * ax);
    float r = 1.0f - p * e;
    return copysignf(r, x);
}

__device__ __forceinline__ float gelu_fast(float x) {
    return 0.5f * x * (1.0f + erf_fast(x * 0.70710678118654752440f));
}

__device__ __forceinline__ float sigmoid_fast(float x) {
    float e = __expf(-x);
    return __builtin_amdgcn_rcpf(1.0f + e);
}

__device__ __forceinline__ float tanh_fast(float x) {
    float e = __expf(2.0f * x);
    return 1.0f - 2.0f * __builtin_amdgcn_rcpf(e + 1.0f);
}

__device__ __forceinline__ v8bf cvt8(const float* __restrict__ p) {
    float4 f0 = *(const float4*)p;
    float4 f1 = *(const float4*)(p + 4);
    v8bf r;
    r[0] = (__bf16)f0.x; r[1] = (__bf16)f0.y; r[2] = (__bf16)f0.z; r[3] = (__bf16)f0.w;
    r[4] = (__bf16)f1.x; r[5] = (__bf16)f1.y; r[6] = (__bf16)f1.z; r[7] = (__bf16)f1.w;
    return r;
}

// ---------------------------------------------------------------------------
__global__ __launch_bounds__(256) void k_zero(int* __restrict__ counts) {
    int i = blockIdx.x * 256 + threadIdx.x;
    if (i < N_NODES) counts[i] = 0;
}

// ---------------------------------------------------------------------------
// Fused pre-pass: [0,712) weight cvt | [712,744) relpart | [744,...) histogram.
__global__ __launch_bounds__(256) void k_pre(const float* __restrict__ msgW,
                                             const float* __restrict__ W1,
                                             const float* __restrict__ W2,
                                             const float* __restrict__ wih,
                                             const float* __restrict__ whh,
                                             __bf16* __restrict__ WB,
                                             const float* __restrict__ rel_emb,
                                             const float* __restrict__ msg_b,
                                             __bf16* __restrict__ RPB,
                                             const int* __restrict__ ei,
                                             int* __restrict__ counts) {
    int bid = blockIdx.x;
    int t = threadIdx.x;
    if (bid < 712) {
        int i = bid * 256 + t;
        float v;
        if (i < 32768) {
            int j = i >> 7, k = i & 127;
            v = (j < 128) ? msgW[j * CAT + k] : msgW[(j - 128) * CAT + 128 + k];
        } else if (i < 65536) {
            int ii = i - 32768; int j = ii >> 7, k = ii & 127;
            v = (j < 128) ? W1[j * CAT + k] : W1[(j - 128) * CAT + 128 + k];
        } else if (i < 81920) {
            int ii = i - 65536; int j = ii >> 7, k = ii & 127;
            v = W1[j * CAT + 256 + k];
        } else if (i < 83968) {
            v = W2[i - 81920];
        } else if (i < 133120) {
            v = wih[i - 83968];
        } else {
            v = whh[i - 133120];
        }
        WB[i] = (__bf16)v;
    } else if (bid < 744) {
        int r = (bid - 712) * 2 + (t >> 7);
        int j = t & 127;
        const float* er = rel_emb + r * D;
        const float* wr = msgW + j * CAT + 2 * D;
        float acc = msg_b[j];
        #pragma unroll 8
        for (int k = 0; k < D; ++k) acc += er[k] * wr[k];
        RPB[r * D + j] = (__bf16)acc;
    } else {
        int e = (bid - 744) * 256 + t;
        if (e < N_EDGES) atomicAdd(&counts[ei[N_EDGES + e]], 1);
    }
}

// ---------------------------------------------------------------------------
// Single-block scan, 1024 threads.
__global__ __launch_bounds__(1024) void k_scan(const int* __restrict__ counts,
                                               int* __restrict__ offsets,
                                               int* __restrict__ cursor) {
    __shared__ int part[1024];
    int t = threadIdx.x;
    const int CH = 49;                         // 1024*49 = 50176 >= 50000
    int lo = t * CH, hi = min(lo + CH, N_NODES);
    int s = 0;
    for (int i = lo; i < hi; ++i) s += counts[i];
    part[t] = s;
    __syncthreads();
    for (int d = 1; d < 1024; d <<= 1) {
        int v = (t >= d) ? part[t - d] : 0;
        __syncthreads();
        part[t] += v;
        __syncthreads();
    }
    int run = (t == 0) ? 0 : part[t - 1];
    for (int i = lo; i < hi; ++i) {
        offsets[i] = run;
        cursor[i] = run;
        run += counts[i];
    }
    if (t == 1023) offsets[N_NODES] = run;
}

// ---------------------------------------------------------------------------
// MERGED: blocks [0,1954) scatter edges into CSR; blocks [1954,...) do the
// nf -> PSTB projection. Both depend only on {k_pre, k_scan}; merging removes
// a launch gap and overlaps the scatter's atomic drain with MFMA work.
__global__ __launch_bounds__(256) void k_scatter_proj(const int* __restrict__ ei,
                                                      int* __restrict__ cursor,
                                                      int* __restrict__ elist,
                                                      const float* __restrict__ in,
                                                      const __bf16* __restrict__ wb,
                                                      __bf16* __restrict__ out) {
    const int EBLK = (N_EDGES + 255) / 256;    // 1954
    int bid = blockIdx.x;
    int t = threadIdx.x;
    if (bid < EBLK) {
        int e = bid * 256 + t;
        if (e < N_EDGES) {
            int slot = atomicAdd(&cursor[ei[N_EDGES + e]], 1);
            elist[slot] = e;
        }
        return;
    }
    // ---- projection part (output-col remap j = half*128 + 8c + jt) ----
    int pb = bid - EBLK;
    int lane = t & 63, wid = t >> 6;
    int g = lane >> 4, c = lane & 15;
    int nbase = pb * 64 + wid * 16;

    int nrow = min(nbase + c, N_NODES - 1);
    const float* ir = in + (size_t)nrow * D + g * 8;
    v8bf afrag[4];
    #pragma unroll
    for (int kc = 0; kc < 4; ++kc) afrag[kc] = cvt8(ir + kc * 32);

    #pragma unroll
    for (int half = 0; half < 2; ++half) {
        v4f acc[8];
        #pragma unroll 2
        for (int jt = 0; jt < 8; ++jt) {
            const __bf16* wr = wb + (size_t)(half * 128 + 8 * c + jt) * 128 + g * 8;
            v4f a4 = (v4f){0.f, 0.f, 0.f, 0.f};
            #pragma unroll
            for (int kc = 0; kc < 4; ++kc)
                a4 = __builtin_amdgcn_mfma_f32_16x16x32_bf16(afrag[kc], *(const v8bf*)(wr + kc * 32), a4, 0, 0, 0);
            acc[jt] = a4;
        }
        #pragma unroll
        for (int r = 0; r < 4; ++r) {
            int node = nbase + g * 4 + r;
            v8bf o;
            #pragma unroll
            for (int jt = 0; jt < 8; ++jt) o[jt] = (__bf16)acc[jt][r];
            if (node < N_NODES)
                *(v8bf*)(out + (size_t)node * 256 + half * 128 + 8 * c) = o;
        }
    }
}

// ---------------------------------------------------------------------------
// Aggregation, atomic-free; 4-edge-deep pipeline (4 independent gather chains
// in flight per iteration; indices staged 8 ahead; clamped redundant loads).
__global__ __launch_bounds__(256) void k_agg(const __bf16* __restrict__ PSTB,
                                             const __bf16* __restrict__ RPB,
                                             const int* __restrict__ ei,
                                             const int* __restrict__ lab,
                                             const int* __restrict__ offsets,
                                             const int* __restrict__ elist,
                                             __bf16* __restrict__ agg) {
    int t = threadIdx.x;
    int wid = t >> 6, lane = t & 63;
    int n = blockIdx.x * 4 + wid;
    if (n >= N_NODES) return;
    int beg = offsets[n], end = offsets[n + 1];

    v2bf ptv = *(const v2bf*)(PSTB + (size_t)n * 256 + 128 + lane * 2);
    float pt0 = (float)ptv[0], pt1 = (float)ptv[1];

    float a0 = 0.f, a1 = 0.f;
    if (beg < end) {
        int mx = end - 1;
        int eA, s0, l0, s1, l1, s2, l2, s3, l3;
        int s4, l4, s5, l5, s6, l6, s7, l7;
        eA = elist[beg];               s0 = ei[eA]; l0 = lab[eA];
        eA = elist[min(beg + 1, mx)];  s1 = ei[eA]; l1 = lab[eA];
        eA = elist[min(beg + 2, mx)];  s2 = ei[eA]; l2 = lab[eA];
        eA = elist[min(beg + 3, mx)];  s3 = ei[eA]; l3 = lab[eA];
        eA = elist[min(beg + 4, mx)];  s4 = ei[eA]; l4 = lab[eA];
        eA = elist[min(beg + 5, mx)];  s5 = ei[eA]; l5 = lab[eA];
        eA = elist[min(beg + 6, mx)];  s6 = ei[eA]; l6 = lab[eA];
        eA = elist[min(beg + 7, mx)];  s7 = ei[eA]; l7 = lab[eA];
        v2bf ps0 = *(const v2bf*)(PSTB + (size_t)s0 * 256 + lane * 2);
        v2bf rp0 = *(const v2bf*)(RPB + (size_t)l0 * D + lane * 2);
        v2bf ps1 = *(const v2bf*)(PSTB + (size_t)s1 * 256 + lane * 2);
        v2bf rp1 = *(const v2bf*)(RPB + (size_t)l1 * D + lane * 2);
        v2bf ps2 = *(const v2bf*)(PSTB + (size_t)s2 * 256 + lane * 2);
        v2bf rp2 = *(const v2bf*)(RPB + (size_t)l2 * D + lane * 2);
        v2bf ps3 = *(const v2bf*)(PSTB + (size_t)s3 * 256 + lane * 2);
        v2bf rp3 = *(const v2bf*)(RPB + (size_t)l3 * D + lane * 2);

        for (int idx = beg; idx < end; idx += 4) {
            v2bf c0 = ps0, d0 = rp0, c1 = ps1, d1 = rp1;
            v2bf c2 = ps2, d2 = rp2, c3 = ps3, d3 = rp3;
            // data for idx+4..idx+7 (from staged indices)
            ps0 = *(const v2bf*)(PSTB + (size_t)s4 * 256 + lane * 2);
            rp0 = *(const v2bf*)(RPB + (size_t)l4 * D + lane * 2);
            ps1 = *(const v2bf*)(PSTB + (size_t)s5 * 256 + lane * 2);
            rp1 = *(const v2bf*)(RPB + (size_t)l5 * D + lane * 2);
            ps2 = *(const v2bf*)(PSTB + (size_t)s6 * 256 + lane * 2);
            rp2 = *(const v2bf*)(RPB + (size_t)l6 * D + lane * 2);
            ps3 = *(const v2bf*)(PSTB + (size_t)s7 * 256 + lane * 2);
            rp3 = *(const v2bf*)(RPB + (size_t)l7 * D + lane * 2);
            // indices for idx+8..idx+11
            int f;
            f = elist[min(idx + 8, mx)];  s4 = ei[f]; l4 = lab[f];
            f = elist[min(idx + 9, mx)];  s5 = ei[f]; l5 = lab[f];
            f = elist[min(idx + 10, mx)]; s6 = ei[f]; l6 = lab[f];
            f = elist[min(idx + 11, mx)]; s7 = ei[f]; l7 = lab[f];
            // consume
            a0 += gelu_fast((float)c0[0] + pt0 + (float)d0[0]);
            a1 += gelu_fast((float)c0[1] + pt1 + (float)d0[1]);
            if (idx + 1 < end) {
                a0 += gelu_fast((float)c1[0] + pt0 + (float)d1[0]);
                a1 += gelu_fast((float)c1[1] + pt1 + (float)d1[1]);
            }
            if (idx + 2 < end) {
                a0 += gelu_fast((float)c2[0] + pt0 + (float)d2[0]);
                a1 += gelu_fast((float)c2[1] + pt1 + (float)d2[1]);
            }
            if (idx + 3 < end) {
                a0 += gelu_fast((float)c3[0] + pt0 + (float)d3[0]);
                a1 += gelu_fast((float)c3[1] + pt1 + (float)d3[1]);
            }
        }
    }
    v2bf o; o[0] = (__bf16)a0; o[1] = (__bf16)a1;
    *(v2bf*)(agg + (size_t)n * D + lane * 2) = o;
}

// ---------------------------------------------------------------------------
// FUSED GRU + projection (r14 structure unchanged).
__global__ __launch_bounds__(256) void k_gru_fused(const __bf16* __restrict__ agg,
                                                   const float* __restrict__ nf,
                                                   const __bf16* __restrict__ WIH,
                                                   const __bf16* __restrict__ WHH,
                                                   const float* __restrict__ b_ih,
                                                   const float* __restrict__ b_hh,
                                                   const __bf16* __restrict__ WQ1,
                                                   __bf16* __restrict__ QSTB) {
    __shared__ __align__(16) __bf16 nfu_s[64][128];   // 16 KB
    int t = threadIdx.x;
    int lane = t & 63, wid = t >> 6;
    int g = lane >> 4, c = lane & 15;
    int nbase = blockIdx.x * 64 + wid * 16;

    int nrow = min(nbase + c, N_NODES - 1);
    const __bf16* ar = agg + (size_t)nrow * D + g * 8;
    const float* hr = nf + (size_t)nrow * D + g * 8;
    v8bf afrag[4], hfrag[4];
    #pragma unroll
    for (int kc = 0; kc < 4; ++kc) {
        afrag[kc] = *(const v8bf*)(ar + kc * 32);
        hfrag[kc] = cvt8(hr + kc * 32);
    }

    float h8[4][8];
    #pragma unroll
    for (int r = 0; r < 4; ++r) {
        int node = min(nbase + g * 4 + r, N_NODES - 1);
        float4 f0 = *(const float4*)(nf + (size_t)node * D + 8 * c);
        float4 f1 = *(const float4*)(nf + (size_t)node * D + 8 * c + 4);
        h8[r][0]=f0.x; h8[r][1]=f0.y; h8[r][2]=f0.z; h8[r][3]=f0.w;
        h8[r][4]=f1.x; h8[r][5]=f1.y; h8[r][6]=f1.z; h8[r][7]=f1.w;
    }

    v8bf o[4];
    for (int jt = 0; jt < 8; ++jt) {
        int j = 8 * c + jt;
        const __bf16* wir = WIH + (size_t)j * 128 + g * 8;
        const __bf16* whr = WHH + (size_t)j * 128 + g * 8;
        v4f a_ir = (v4f){0.f,0.f,0.f,0.f}, a_iz = a_ir, a_in = a_ir;
        v4f a_hr = a_ir, a_hz = a_ir, a_hn = a_ir;
        #pragma unroll
        for (int kc = 0; kc < 4; ++kc) {
            a_ir = __builtin_amdgcn_mfma_f32_16x16x32_bf16(afrag[kc], *(const v8bf*)(wir + kc * 32), a_ir, 0, 0, 0);
            a_iz = __builtin_amdgcn_mfma_f32_16x16x32_bf16(afrag[kc], *(const v8bf*)(wir + 128 * 128 + kc * 32), a_iz, 0, 0, 0);
            a_in = __builtin_amdgcn_mfma_f32_16x16x32_bf16(afrag[kc], *(const v8bf*)(wir + 256 * 128 + kc * 32), a_in, 0, 0, 0);
            a_hr = __builtin_amdgcn_mfma_f32_16x16x32_bf16(hfrag[kc], *(const v8bf*)(whr + kc * 32), a_hr, 0, 0, 0);
            a_hz = __builtin_amdgcn_mfma_f32_16x16x32_bf16(hfrag[kc], *(const v8bf*)(whr + 128 * 128 + kc * 32), a_hz, 0, 0, 0);
            a_hn = __builtin_amdgcn_mfma_f32_16x16x32_bf16(hfrag[kc], *(const v8bf*)(whr + 256 * 128 + kc * 32), a_hn, 0, 0, 0);
        }
        float bir = b_ih[j], biz = b_ih[128 + j], bin = b_ih[256 + j];
        float bhr = b_hh[j], bhz = b_hh[128 + j], bhn = b_hh[256 + j];
        #pragma unroll
        for (int r = 0; r < 4; ++r) {
            float irv = a_ir[r] + bir, hrv = a_hr[r] + bhr;
            float izv = a_iz[r] + biz, hzv = a_hz[r] + bhz;
            float inv = a_in[r] + bin, hnv = a_hn[r] + bhn;
            float rg = sigmoid_fast(irv + hrv);
            float zg = sigmoid_fast(izv + hzv);
            float ng = tanh_fast(inv + rg * hnv);
            o[r][jt] = (__bf16)((1.f - zg) * ng + zg * h8[r][jt]);
        }
    }
    #pragma unroll
    for (int r = 0; r < 4; ++r) {
        int lr = wid * 16 + g * 4 + r;
        *(v8bf*)&nfu_s[lr][8 * (c ^ (lr & 7))] = o[r];
    }

    int lr2 = wid * 16 + c;
    v8bf pfrag[4];
    #pragma unroll
    for (int kc = 0; kc < 4; ++kc)
        pfrag[kc] = *(const v8bf*)&nfu_s[lr2][8 * ((g + 4 * kc) ^ (c & 7))];

    #pragma unroll
    for (int half = 0; half < 2; ++half) {
        v4f acc[8];
        #pragma unroll 2
        for (int jt = 0; jt < 8; ++jt) {
            const __bf16* wr = WQ1 + (size_t)(half * 128 + 8 * c + jt) * 128 + g * 8;
            v4f a4 = (v4f){0.f, 0.f, 0.f, 0.f};
            #pragma unroll
            for (int kc = 0; kc < 4; ++kc)
                a4 = __builtin_amdgcn_mfma_f32_16x16x32_bf16(pfrag[kc], *(const v8bf*)(wr + kc * 32), a4, 0, 0, 0);
            acc[jt] = a4;
        }
        #pragma unroll
        for (int r = 0; r < 4; ++r) {
            int node = nbase + g * 4 + r;
            v8bf oo;
            #pragma unroll
            for (int jt = 0; jt < 8; ++jt) oo[jt] = (__bf16)acc[jt][r];
            if (node < N_NODES)
                *(v8bf*)(QSTB + (size_t)node * 256 + half * 128 + 8 * c) = oo;
        }
    }
}

// ---------------------------------------------------------------------------
// MFMA classifier v7 (REVERTED to r14: 256-thread, 4-wave, grid 768,
// 64-edge tiles). Persistent blocks + software pipeline: ef[T] issued iter
// T-1 BEFORE gathers[T] (older -> its wait doesn't drain them); gathers[T]
// consumed at epilogue (full iteration in flight); idx[T+1] staged.
// V3 in LDS (GEMM1 waits are lgkmcnt-only). LDS 48KB -> 3 blocks/CU.
__global__ __launch_bounds__(256) void k_cls_mfma(const float* __restrict__ ef,
                                                  const __bf16* __restrict__ QSTB,
                                                  const __bf16* __restrict__ V3,
                                                  const float* __restrict__ b1,
                                                  const __bf16* __restrict__ W2B,
                                                  const float* __restrict__ b2,
                                                  const int* __restrict__ ei,
                                                  float* __restrict__ out) {
    __shared__ __align__(16) __bf16 v3_s[128][128];  // 32 KB
    __shared__ __align__(16) __bf16 hc_s[64][128];   // 16 KB
    int t = threadIdx.x;
    int lane = t & 63, w = t >> 6;
    int g = lane >> 4, c = lane & 15;
    const int ntile = (N_EDGES + 63) / 64;
    const int stride = gridDim.x;

    int tile = blockIdx.x;

    // hoisted invariants
    v8bf w2frag[4];
    #pragma unroll
    for (int kc = 0; kc < 4; ++kc)
        w2frag[kc] = *(const v8bf*)(W2B + c * 128 + (g + 4 * kc) * 8);
    float4 b1a = *(const float4*)(b1 + 8 * c);
    float4 b1b = *(const float4*)(b1 + 8 * c + 4);
    float b1r[8] = {b1a.x, b1a.y, b1a.z, b1a.w, b1b.x, b1b.y, b1b.z, b1b.w};
    float b2c = b2[c];

    // prologue: ef[tile] + idx[tile]
    float4 efraw[8];
    int sr[4], tr[4];
    {
        int e_base = tile * 64 + w * 16;
        int er = min(e_base + c, N_EDGES - 1);
        const float* efr = ef + (size_t)er * D + g * 8;
        #pragma unroll
        for (int kc = 0; kc < 4; ++kc) {
            efraw[2 * kc]     = *(const float4*)(efr + kc * 32);
            efraw[2 * kc + 1] = *(const float4*)(efr + kc * 32 + 4);
        }
        #pragma unroll
        for (int r = 0; r < 4; ++r) {
            int e = min(e_base + g * 4 + r, N_EDGES - 1);
            sr[r] = ei[e];
            tr[r] = ei[N_EDGES + e];
        }
    }

    // stage V3 into LDS, chunk-swizzled (once per block)
    #pragma unroll
    for (int i = 0; i < 8; ++i) {
        int idx = t * 8 + i;
        int row = idx >> 4, ch = idx & 15;
        v8bf v = *(const v8bf*)(V3 + row * 128 + ch * 8);
        *(v8bf*)&v3_s[row][8 * (ch ^ ((row >> 3) & 7))] = v;
    }
    __syncthreads();

    // prologue: issue gathers[tile]; load idx[tile+stride]
    v8bf qs[4], qt[4];
    #pragma unroll
    for (int r = 0; r < 4; ++r) {
        qs[r] = *(const v8bf*)(QSTB + (size_t)sr[r] * 256 + 8 * c);
        qt[r] = *(const v8bf*)(QSTB + (size_t)tr[r] * 256 + 128 + 8 * c);
    }
    int srn[4], trn[4];
    if (tile + stride < ntile) {
        int nb = (tile + stride) * 64 + w * 16;
        #pragma unroll
        for (int r = 0; r < 4; ++r) {
            int e = min(nb + g * 4 + r, N_EDGES - 1);
            srn[r] = ei[e];
            trn[r] = ei[N_EDGES + e];
        }
    }

    while (tile < ntile) {
        int nxt = tile + stride;
        int e_base = tile * 64 + w * 16;

        // (1) A-fragments from efraw (older than gathers -> no drain)
        v8bf afrag[4];
        #pragma unroll
        for (int kc = 0; kc < 4; ++kc) {
            v8bf a;
            float4 f0 = efraw[2 * kc], f1 = efraw[2 * kc + 1];
            a[0] = (__bf16)f0.x; a[1] = (__bf16)f0.y; a[2] = (__bf16)f0.z; a[3] = (__bf16)f0.w;
            a[4] = (__bf16)f1.x; a[5] = (__bf16)f1.y; a[6] = (__bf16)f1.z; a[7] = (__bf16)f1.w;
            afrag[kc] = a;
        }

        // (2) issue ef[T+1]
        if (nxt < ntile) {
            int nb = nxt * 64 + w * 16;
            int er = min(nb + c, N_EDGES - 1);
            const float* efr = ef + (size_t)er * D + g * 8;
            #pragma unroll
            for (int kc = 0; kc < 4; ++kc) {
                efraw[2 * kc]     = *(const float4*)(efr + kc * 32);
                efraw[2 * kc + 1] = *(const float4*)(efr + kc * 32 + 4);
            }
        }

        // (3) issue gathers[T+1] from srn/trn
        v8bf qsn[4], qtn[4];
        if (nxt < ntile) {
            #pragma unroll
            for (int r = 0; r < 4; ++r) {
                qsn[r] = *(const v8bf*)(QSTB + (size_t)srn[r] * 256 + 8 * c);
                qtn[r] = *(const v8bf*)(QSTB + (size_t)trn[r] * 256 + 128 + 8 * c);
            }
        }

        // (4) issue idx[T+2]
        if (nxt + stride < ntile) {
            int nb = (nxt + stride) * 64 + w * 16;
            #pragma unroll
            for (int r = 0; r < 4; ++r) {
                int e = min(nb + g * 4 + r, N_EDGES - 1);
                srn[r] = ei[e];
                trn[r] = ei[N_EDGES + e];
            }
        }

        // (5) GEMM1 from LDS (lgkmcnt only)
        v4f acc[8];
        #pragma unroll
        for (int jt = 0; jt < 8; ++jt) {
            int row = 8 * c + jt;
            v4f a4 = (v4f){0.f, 0.f, 0.f, 0.f};
            #pragma unroll
            for (int kc = 0; kc < 4; ++kc) {
                v8bf bb = *(const v8bf*)&v3_s[row][8 * ((g + 4 * kc) ^ (c & 7))];
                a4 = __builtin_amdgcn_mfma_f32_16x16x32_bf16(afrag[kc], bb, a4, 0, 0, 0);
            }
            acc[jt] = a4;
        }

        // (6) epilogue with gathers[T] (a full iteration in flight)
        #pragma unroll
        for (int r = 0; r < 4; ++r) {
            int el = w * 16 + g * 4 + r;
            v8bf o;
            #pragma unroll
            for (int jt = 0; jt < 8; ++jt) {
                float v = acc[jt][r] + (float)qs[r][jt] + (float)qt[r][jt] + b1r[jt];
                o[jt] = (__bf16)gelu_fast(v);
            }
            *(v8bf*)&hc_s[el][8 * (c ^ (el & 7))] = o;
        }

        // (7) GEMM2 + store (hc round-trip wave-local)
        v4f acc2 = (v4f){0.f, 0.f, 0.f, 0.f};
        int arow = w * 16 + c;
        #pragma unroll
        for (int kc = 0; kc < 4; ++kc) {
            int ch = g + 4 * kc;
            v8bf aa = *(const v8bf*)&hc_s[arow][8 * (ch ^ (c & 7))];
            acc2 = __builtin_amdgcn_mfma_f32_16x16x32_bf16(aa, w2frag[kc], acc2, 0, 0, 0);
        }
        #pragma unroll
        for (int r = 0; r < 4; ++r) {
            int e = e_base + g * 4 + r;
            if (e < N_EDGES) out[(size_t)e * 16 + c] = acc2[r] + b2c;
        }

        // (8) rotate
        #pragma unroll
        for (int r = 0; r < 4; ++r) { qs[r] = qsn[r]; qt[r] = qtn[r]; }
        tile = nxt;
    }
}

// ---------------------------------------------------------------------------
extern "C" void kernel_launch(void* const* d_in, const int* in_sizes, int n_in,
                              void* d_out, int out_size, void* d_ws, size_t ws_size,
                              hipStream_t stream) {
    const float* nf   = (const float*)d_in[0];
    const float* ef   = (const float*)d_in[1];
    const int*   ei   = (const int*)d_in[2];
    const int*   lab  = (const int*)d_in[3];
    const float* rel  = (const float*)d_in[4];
    const float* msgW = (const float*)d_in[5];
    const float* msgb = (const float*)d_in[6];
    const float* wih  = (const float*)d_in[7];
    const float* whh  = (const float*)d_in[8];
    const float* bih  = (const float*)d_in[9];
    const float* bhh  = (const float*)d_in[10];
    const float* W1   = (const float*)d_in[11];
    const float* b1   = (const float*)d_in[12];
    const float* W2   = (const float*)d_in[13];
    const float* b2   = (const float*)d_in[14];
    float* out = (float*)d_out;

    char* ws = (char*)d_ws;
    __bf16* WB      = (__bf16*)(ws);                  // 364.5 KB
    __bf16* RPB     = (__bf16*)(ws + 524288);         // 16 KB
    int*    offsets = (int*)(ws + 1048576);           // 200 KB (N+1)
    int*    counts  = (int*)(ws + 1310720);           // 200 KB
    int*    cursor  = (int*)(ws + 1572864);           // 200 KB
    int*    elist   = (int*)(ws + 1835008);           // 2 MB
    __bf16* PSTB    = (__bf16*)(ws + 4194304);        // 25.6 MB
    __bf16* AGG     = (__bf16*)(ws + 33554432);       // 12.8 MB
    __bf16* QSTB    = PSTB;                           // reuse after k_agg

    __bf16* WP1 = WB;
    __bf16* WQ1 = WB + 32768;
    __bf16* V3  = WB + 65536;
    __bf16* W2B = WB + 81920;
    __bf16* WIH = WB + 83968;
    __bf16* WHH = WB + 133120;

    int nblk = (N_NODES + 63) / 64;                   // 782
    int eblk = (N_EDGES + 255) / 256;                 // 1954

    k_zero<<<(N_NODES + 255) / 256, 256, 0, stream>>>(counts);
    k_pre<<<744 + eblk, 256, 0, stream>>>(msgW, W1, W2, wih, whh, WB,
                                          rel, msgb, RPB, ei, counts);
    k_scan<<<1, 1024, 0, stream>>>(counts, offsets, cursor);
    k_scatter_proj<<<eblk + nblk, 256, 0, stream>>>(ei, cursor, elist, nf, WP1, PSTB);
    k_agg<<<(N_NODES + 3) / 4, 256, 0, stream>>>(PSTB, RPB, ei, lab, offsets, elist, AGG);
    k_gru_fused<<<nblk, 256, 0, stream>>>(AGG, nf, WIH, WHH, bih, bhh, WQ1, QSTB);
    k_cls_mfma<<<768, 256, 0, stream>>>(ef, QSTB, V3, b1, W2B, b2, ei, out);
}

// Round 17
// 511.157 us; speedup vs baseline: 1.1330x; 1.0250x over previous
//
#include <hip/hip_runtime.h>
#include <math.h>

#define N_NODES 50000
#define N_EDGES 500000
#define D 128
#define CAT 384

typedef __bf16 v8bf __attribute__((ext_vector_type(8)));
typedef __bf16 v2bf __attribute__((ext_vector_type(2)));
typedef float v4f __attribute__((ext_vector_type(4)));

// ---------------------------------------------------------------------------
// Fast transcendentals on the v_exp_f32 / v_rcp_f32 pipes.
__device__ __forceinline__ float erf_fast(float x) {
    float ax = fabsf(x);
    float t = __builtin_amdgcn_rcpf(fmaf(0.3275911f, ax, 1.0f));
    float p = fmaf(1.061405429f, t, -1.453152027f);
    p = fmaf(p, t, 1.421413741f);
    p = fmaf(p, t, -0.284496736f);
    p = fmaf(p, t, 0.254829592f);
    p = p * t;
    float e = __expf(-ax * ax);
    float r = 1.0f - p * e;
    return copysignf(r, x);
}

__device__ __forceinline__ float gelu_fast(float x) {
    return 0.5f * x * (1.0f + erf_fast(x * 0.70710678118654752440f));
}

__device__ __forceinline__ float sigmoid_fast(float x) {
    float e = __expf(-x);
    return __builtin_amdgcn_rcpf(1.0f + e);
}

__device__ __forceinline__ float tanh_fast(float x) {
    float e = __expf(2.0f * x);
    return 1.0f - 2.0f * __builtin_amdgcn_rcpf(e + 1.0f);
}

__device__ __forceinline__ v8bf cvt8(const float* __restrict__ p) {
    float4 f0 = *(const float4*)p;
    float4 f1 = *(const float4*)(p + 4);
    v8bf r;
    r[0] = (__bf16)f0.x; r[1] = (__bf16)f0.y; r[2] = (__bf16)f0.z; r[3] = (__bf16)f0.w;
    r[4] = (__bf16)f1.x; r[5] = (__bf16)f1.y; r[6] = (__bf16)f1.z; r[7] = (__bf16)f1.w;
    return r;
}

// ---------------------------------------------------------------------------
__global__ __launch_bounds__(256) void k_zero(int* __restrict__ counts) {
    int i = blockIdx.x * 256 + threadIdx.x;
    if (i < N_NODES) counts[i] = 0;
}

// ---------------------------------------------------------------------------
// Fused pre-pass: [0,712) weight cvt | [712,744) relpart | [744,...) histogram.
__global__ __launch_bounds__(256) void k_pre(const float* __restrict__ msgW,
                                             const float* __restrict__ W1,
                                             const float* __restrict__ W2,
                                             const float* __restrict__ wih,
                                             const float* __restrict__ whh,
                                             __bf16* __restrict__ WB,
                                             const float* __restrict__ rel_emb,
                                             const float* __restrict__ msg_b,
                                             __bf16* __restrict__ RPB,
                                             const int* __restrict__ ei,
                                             int* __restrict__ counts) {
    int bid = blockIdx.x;
    int t = threadIdx.x;
    if (bid < 712) {
        int i = bid * 256 + t;
        float v;
        if (i < 32768) {
            int j = i >> 7, k = i & 127;
            v = (j < 128) ? msgW[j * CAT + k] : msgW[(j - 128) * CAT + 128 + k];
        } else if (i < 65536) {
            int ii = i - 32768; int j = ii >> 7, k = ii & 127;
            v = (j < 128) ? W1[j * CAT + k] : W1[(j - 128) * CAT + 128 + k];
        } else if (i < 81920) {
            int ii = i - 65536; int j = ii >> 7, k = ii & 127;
            v = W1[j * CAT + 256 + k];
        } else if (i < 83968) {
            v = W2[i - 81920];
        } else if (i < 133120) {
            v = wih[i - 83968];
        } else {
            v = whh[i - 133120];
        }
        WB[i] = (__bf16)v;
    } else if (bid < 744) {
        int r = (bid - 712) * 2 + (t >> 7);
        int j = t & 127;
        const float* er = rel_emb + r * D;
        const float* wr = msgW + j * CAT + 2 * D;
        float acc = msg_b[j];
        #pragma unroll 8
        for (int k = 0; k < D; ++k) acc += er[k] * wr[k];
        RPB[r * D + j] = (__bf16)acc;
    } else {
        int e = (bid - 744) * 256 + t;
        if (e < N_EDGES) atomicAdd(&counts[ei[N_EDGES + e]], 1);
    }
}

// ---------------------------------------------------------------------------
// MFMA node projection (fp32 input), output-col remap j = half*128 + 8c + jt.
__global__ __launch_bounds__(256) void k_proj2_f32(const float* __restrict__ in,
                                                   const __bf16* __restrict__ wb,
                                                   __bf16* __restrict__ out) {
    int t = threadIdx.x;
    int lane = t & 63, wid = t >> 6;
    int g = lane >> 4, c = lane & 15;
    int nbase = blockIdx.x * 64 + wid * 16;

    int nrow = min(nbase + c, N_NODES - 1);
    const float* ir = in + (size_t)nrow * D + g * 8;
    v8bf afrag[4];
    #pragma unroll
    for (int kc = 0; kc < 4; ++kc) afrag[kc] = cvt8(ir + kc * 32);

    #pragma unroll
    for (int half = 0; half < 2; ++half) {
        v4f acc[8];
        #pragma unroll 2
        for (int jt = 0; jt < 8; ++jt) {
            const __bf16* wr = wb + (size_t)(half * 128 + 8 * c + jt) * 128 + g * 8;
            v4f a4 = (v4f){0.f, 0.f, 0.f, 0.f};
            #pragma unroll
            for (int kc = 0; kc < 4; ++kc)
                a4 = __builtin_amdgcn_mfma_f32_16x16x32_bf16(afrag[kc], *(const v8bf*)(wr + kc * 32), a4, 0, 0, 0);
            acc[jt] = a4;
        }
        #pragma unroll
        for (int r = 0; r < 4; ++r) {
            int node = nbase + g * 4 + r;
            v8bf o;
            #pragma unroll
            for (int jt = 0; jt < 8; ++jt) o[jt] = (__bf16)acc[jt][r];
            if (node < N_NODES)
                *(v8bf*)(out + (size_t)node * 256 + half * 128 + 8 * c) = o;
        }
    }
}

// ---------------------------------------------------------------------------
// Single-block scan, 1024 threads.
__global__ __launch_bounds__(1024) void k_scan(const int* __restrict__ counts,
                                               int* __restrict__ offsets,
                                               int* __restrict__ cursor) {
    __shared__ int part[1024];
    int t = threadIdx.x;
    const int CH = 49;                         // 1024*49 = 50176 >= 50000
    int lo = t * CH, hi = min(lo + CH, N_NODES);
    int s = 0;
    for (int i = lo; i < hi; ++i) s += counts[i];
    part[t] = s;
    __syncthreads();
    for (int d = 1; d < 1024; d <<= 1) {
        int v = (t >= d) ? part[t - d] : 0;
        __syncthreads();
        part[t] += v;
        __syncthreads();
    }
    int run = (t == 0) ? 0 : part[t - 1];
    for (int i = lo; i < hi; ++i) {
        offsets[i] = run;
        cursor[i] = run;
        run += counts[i];
    }
    if (t == 1023) offsets[N_NODES] = run;
}

__global__ __launch_bounds__(256) void k_scatter(const int* __restrict__ ei,
                                                 int* __restrict__ cursor,
                                                 int* __restrict__ elist) {
    int e = blockIdx.x * 256 + threadIdx.x;
    if (e < N_EDGES) {
        int slot = atomicAdd(&cursor[ei[N_EDGES + e]], 1);
        elist[slot] = e;
    }
}

// ---------------------------------------------------------------------------
// Aggregation, atomic-free; 2-deep index / 1-deep row-data prefetch (r14).
__global__ __launch_bounds__(256) void k_agg(const __bf16* __restrict__ PSTB,
                                             const __bf16* __restrict__ RPB,
                                             const int* __restrict__ ei,
                                             const int* __restrict__ lab,
                                             const int* __restrict__ offsets,
                                             const int* __restrict__ elist,
                                             __bf16* __restrict__ agg) {
    int t = threadIdx.x;
    int wid = t >> 6, lane = t & 63;
    int n = blockIdx.x * 4 + wid;
    if (n >= N_NODES) return;
    int beg = offsets[n], end = offsets[n + 1];

    v2bf ptv = *(const v2bf*)(PSTB + (size_t)n * 256 + 128 + lane * 2);
    float pt0 = (float)ptv[0], pt1 = (float)ptv[1];

    float a0 = 0.f, a1 = 0.f;
    if (beg < end) {
        int mx = end - 1;
        int eA = elist[beg];
        int eB = elist[min(beg + 1, mx)];
        int e2 = elist[min(beg + 2, mx)];
        int e3 = elist[min(beg + 3, mx)];
        int sA = ei[eA], lA = lab[eA];
        int sB = ei[eB], lB = lab[eB];
        int s2 = ei[e2], l2 = lab[e2];
        int s3 = ei[e3], l3 = lab[e3];
        v2bf psA = *(const v2bf*)(PSTB + (size_t)sA * 256 + lane * 2);
        v2bf rpA = *(const v2bf*)(RPB + (size_t)lA * D + lane * 2);
        v2bf psB = *(const v2bf*)(PSTB + (size_t)sB * 256 + lane * 2);
        v2bf rpB = *(const v2bf*)(RPB + (size_t)lB * D + lane * 2);

        for (int idx = beg; idx < end; idx += 2) {
            v2bf cpsA = psA, crpA = rpA, cpsB = psB, crpB = rpB;
            bool hasB = (idx + 1 < end);
            psA = *(const v2bf*)(PSTB + (size_t)s2 * 256 + lane * 2);
            rpA = *(const v2bf*)(RPB + (size_t)l2 * D + lane * 2);
            psB = *(const v2bf*)(PSTB + (size_t)s3 * 256 + lane * 2);
            rpB = *(const v2bf*)(RPB + (size_t)l3 * D + lane * 2);
            int e4 = elist[min(idx + 4, mx)];
            int e5 = elist[min(idx + 5, mx)];
            s2 = ei[e4]; l2 = lab[e4];
            s3 = ei[e5]; l3 = lab[e5];
            a0 += gelu_fast((float)cpsA[0] + pt0 + (float)crpA[0]);
            a1 += gelu_fast((float)cpsA[1] + pt1 + (float)crpA[1]);
            if (hasB) {
                a0 += gelu_fast((float)cpsB[0] + pt0 + (float)crpB[0]);
                a1 += gelu_fast((float)cpsB[1] + pt1 + (float)crpB[1]);
            }
        }
    }
    v2bf o; o[0] = (__bf16)a0; o[1] = (__bf16)a1;
    *(v2bf*)(agg + (size_t)n * D + lane * 2) = o;
}

// ---------------------------------------------------------------------------
// FUSED GRU + projection (r14 structure).
__global__ __launch_bounds__(256) void k_gru_fused(const __bf16* __restrict__ agg,
                                                   const float* __restrict__ nf,
                                                   const __bf16* __restrict__ WIH,
                                                   const __bf16* __restrict__ WHH,
                                                   const float* __restrict__ b_ih,
                                                   const float* __restrict__ b_hh,
                                                   const __bf16* __restrict__ WQ1,
                                                   __bf16* __restrict__ QSTB) {
    __shared__ __align__(16) __bf16 nfu_s[64][128];   // 16 KB
    int t = threadIdx.x;
    int lane = t & 63, wid = t >> 6;
    int g = lane >> 4, c = lane & 15;
    int nbase = blockIdx.x * 64 + wid * 16;

    int nrow = min(nbase + c, N_NODES - 1);
    const __bf16* ar = agg + (size_t)nrow * D + g * 8;
    const float* hr = nf + (size_t)nrow * D + g * 8;
    v8bf afrag[4], hfrag[4];
    #pragma unroll
    for (int kc = 0; kc < 4; ++kc) {
        afrag[kc] = *(const v8bf*)(ar + kc * 32);
        hfrag[kc] = cvt8(hr + kc * 32);
    }

    float h8[4][8];
    #pragma unroll
    for (int r = 0; r < 4; ++r) {
        int node = min(nbase + g * 4 + r, N_NODES - 1);
        float4 f0 = *(const float4*)(nf + (size_t)node * D + 8 * c);
        float4 f1 = *(const float4*)(nf + (size_t)node * D + 8 * c + 4);
        h8[r][0]=f0.x; h8[r][1]=f0.y; h8[r][2]=f0.z; h8[r][3]=f0.w;
        h8[r][4]=f1.x; h8[r][5]=f1.y; h8[r][6]=f1.z; h8[r][7]=f1.w;
    }

    v8bf o[4];
    for (int jt = 0; jt < 8; ++jt) {
        int j = 8 * c + jt;
        const __bf16* wir = WIH + (size_t)j * 128 + g * 8;
        const __bf16* whr = WHH + (size_t)j * 128 + g * 8;
        v4f a_ir = (v4f){0.f,0.f,0.f,0.f}, a_iz = a_ir, a_in = a_ir;
        v4f a_hr = a_ir, a_hz = a_ir, a_hn = a_ir;
        #pragma unroll
        for (int kc = 0; kc < 4; ++kc) {
            a_ir = __builtin_amdgcn_mfma_f32_16x16x32_bf16(afrag[kc], *(const v8bf*)(wir + kc * 32), a_ir, 0, 0, 0);
            a_iz = __builtin_amdgcn_mfma_f32_16x16x32_bf16(afrag[kc], *(const v8bf*)(wir + 128 * 128 + kc * 32), a_iz, 0, 0, 0);
            a_in = __builtin_amdgcn_mfma_f32_16x16x32_bf16(afrag[kc], *(const v8bf*)(wir + 256 * 128 + kc * 32), a_in, 0, 0, 0);
            a_hr = __builtin_amdgcn_mfma_f32_16x16x32_bf16(hfrag[kc], *(const v8bf*)(whr + kc * 32), a_hr, 0, 0, 0);
            a_hz = __builtin_amdgcn_mfma_f32_16x16x32_bf16(hfrag[kc], *(const v8bf*)(whr + 128 * 128 + kc * 32), a_hz, 0, 0, 0);
            a_hn = __builtin_amdgcn_mfma_f32_16x16x32_bf16(hfrag[kc], *(const v8bf*)(whr + 256 * 128 + kc * 32), a_hn, 0, 0, 0);
        }
        float bir = b_ih[j], biz = b_ih[128 + j], bin = b_ih[256 + j];
        float bhr = b_hh[j], bhz = b_hh[128 + j], bhn = b_hh[256 + j];
        #pragma unroll
        for (int r = 0; r < 4; ++r) {
            float irv = a_ir[r] + bir, hrv = a_hr[r] + bhr;
            float izv = a_iz[r] + biz, hzv = a_hz[r] + bhz;
            float inv = a_in[r] + bin, hnv = a_hn[r] + bhn;
            float rg = sigmoid_fast(irv + hrv);
            float zg = sigmoid_fast(izv + hzv);
            float ng = tanh_fast(inv + rg * hnv);
            o[r][jt] = (__bf16)((1.f - zg) * ng + zg * h8[r][jt]);
        }
    }
    #pragma unroll
    for (int r = 0; r < 4; ++r) {
        int lr = wid * 16 + g * 4 + r;
        *(v8bf*)&nfu_s[lr][8 * (c ^ (lr & 7))] = o[r];
    }

    int lr2 = wid * 16 + c;
    v8bf pfrag[4];
    #pragma unroll
    for (int kc = 0; kc < 4; ++kc)
        pfrag[kc] = *(const v8bf*)&nfu_s[lr2][8 * ((g + 4 * kc) ^ (c & 7))];

    #pragma unroll
    for (int half = 0; half < 2; ++half) {
        v4f acc[8];
        #pragma unroll 2
        for (int jt = 0; jt < 8; ++jt) {
            const __bf16* wr = WQ1 + (size_t)(half * 128 + 8 * c + jt) * 128 + g * 8;
            v4f a4 = (v4f){0.f, 0.f, 0.f, 0.f};
            #pragma unroll
            for (int kc = 0; kc < 4; ++kc)
                a4 = __builtin_amdgcn_mfma_f32_16x16x32_bf16(pfrag[kc], *(const v8bf*)(wr + kc * 32), a4, 0, 0, 0);
            acc[jt] = a4;
        }
        #pragma unroll
        for (int r = 0; r < 4; ++r) {
            int node = nbase + g * 4 + r;
            v8bf oo;
            #pragma unroll
            for (int jt = 0; jt < 8; ++jt) oo[jt] = (__bf16)acc[jt][r];
            if (node < N_NODES)
                *(v8bf*)(QSTB + (size_t)node * 256 + half * 128 + 8 * c) = oo;
        }
    }
}

// ---------------------------------------------------------------------------
// MFMA classifier v7 (r14: 256-thread, 4-wave, grid 768, 64-edge tiles).
// Persistent blocks + software pipeline: ef[T] issued iter T-1 BEFORE
// gathers[T] (older -> its wait doesn't drain them); gathers[T] consumed at
// epilogue (full iteration in flight); idx[T+1] staged. V3 in LDS (GEMM1
// waits are lgkmcnt-only). LDS 48KB -> 3 blocks/CU.
__global__ __launch_bounds__(256) void k_cls_mfma(const float* __restrict__ ef,
                                                  const __bf16* __restrict__ QSTB,
                                                  const __bf16* __restrict__ V3,
                                                  const float* __restrict__ b1,
                                                  const __bf16* __restrict__ W2B,
                                                  const float* __restrict__ b2,
                                                  const int* __restrict__ ei,
                                                  float* __restrict__ out) {
    __shared__ __align__(16) __bf16 v3_s[128][128];  // 32 KB
    __shared__ __align__(16) __bf16 hc_s[64][128];   // 16 KB
    int t = threadIdx.x;
    int lane = t & 63, w = t >> 6;
    int g = lane >> 4, c = lane & 15;
    const int ntile = (N_EDGES + 63) / 64;
    const int stride = gridDim.x;

    int tile = blockIdx.x;

    // hoisted invariants
    v8bf w2frag[4];
    #pragma unroll
    for (int kc = 0; kc < 4; ++kc)
        w2frag[kc] = *(const v8bf*)(W2B + c * 128 + (g + 4 * kc) * 8);
    float4 b1a = *(const float4*)(b1 + 8 * c);
    float4 b1b = *(const float4*)(b1 + 8 * c + 4);
    float b1r[8] = {b1a.x, b1a.y, b1a.z, b1a.w, b1b.x, b1b.y, b1b.z, b1b.w};
    float b2c = b2[c];

    // prologue: ef[tile] + idx[tile]
    float4 efraw[8];
    int sr[4], tr[4];
    {
        int e_base = tile * 64 + w * 16;
        int er = min(e_base + c, N_EDGES - 1);
        const float* efr = ef + (size_t)er * D + g * 8;
        #pragma unroll
        for (int kc = 0; kc < 4; ++kc) {
            efraw[2 * kc]     = *(const float4*)(efr + kc * 32);
            efraw[2 * kc + 1] = *(const float4*)(efr + kc * 32 + 4);
        }
        #pragma unroll
        for (int r = 0; r < 4; ++r) {
            int e = min(e_base + g * 4 + r, N_EDGES - 1);
            sr[r] = ei[e];
            tr[r] = ei[N_EDGES + e];
        }
    }

    // stage V3 into LDS, chunk-swizzled (once per block)
    #pragma unroll
    for (int i = 0; i < 8; ++i) {
        int idx = t * 8 + i;
        int row = idx >> 4, ch = idx & 15;
        v8bf v = *(const v8bf*)(V3 + row * 128 + ch * 8);
        *(v8bf*)&v3_s[row][8 * (ch ^ ((row >> 3) & 7))] = v;
    }
    __syncthreads();

    // prologue: issue gathers[tile]; load idx[tile+stride]
    v8bf qs[4], qt[4];
    #pragma unroll
    for (int r = 0; r < 4; ++r) {
        qs[r] = *(const v8bf*)(QSTB + (size_t)sr[r] * 256 + 8 * c);
        qt[r] = *(const v8bf*)(QSTB + (size_t)tr[r] * 256 + 128 + 8 * c);
    }
    int srn[4], trn[4];
    if (tile + stride < ntile) {
        int nb = (tile + stride) * 64 + w * 16;
        #pragma unroll
        for (int r = 0; r < 4; ++r) {
            int e = min(nb + g * 4 + r, N_EDGES - 1);
            srn[r] = ei[e];
            trn[r] = ei[N_EDGES + e];
        }
    }

    while (tile < ntile) {
        int nxt = tile + stride;
        int e_base = tile * 64 + w * 16;

        // (1) A-fragments from efraw (older than gathers -> no drain)
        v8bf afrag[4];
        #pragma unroll
        for (int kc = 0; kc < 4; ++kc) {
            v8bf a;
            float4 f0 = efraw[2 * kc], f1 = efraw[2 * kc + 1];
            a[0] = (__bf16)f0.x; a[1] = (__bf16)f0.y; a[2] = (__bf16)f0.z; a[3] = (__bf16)f0.w;
            a[4] = (__bf16)f1.x; a[5] = (__bf16)f1.y; a[6] = (__bf16)f1.z; a[7] = (__bf16)f1.w;
            afrag[kc] = a;
        }

        // (2) issue ef[T+1]
        if (nxt < ntile) {
            int nb = nxt * 64 + w * 16;
            int er = min(nb + c, N_EDGES - 1);
            const float* efr = ef + (size_t)er * D + g * 8;
            #pragma unroll
            for (int kc = 0; kc < 4; ++kc) {
                efraw[2 * kc]     = *(const float4*)(efr + kc * 32);
                efraw[2 * kc + 1] = *(const float4*)(efr + kc * 32 + 4);
            }
        }

        // (3) issue gathers[T+1] from srn/trn
        v8bf qsn[4], qtn[4];
        if (nxt < ntile) {
            #pragma unroll
            for (int r = 0; r < 4; ++r) {
                qsn[r] = *(const v8bf*)(QSTB + (size_t)srn[r] * 256 + 8 * c);
                qtn[r] = *(const v8bf*)(QSTB + (size_t)trn[r] * 256 + 128 + 8 * c);
            }
        }

        // (4) issue idx[T+2]
        if (nxt + stride < ntile) {
            int nb = (nxt + stride) * 64 + w * 16;
            #pragma unroll
            for (int r = 0; r < 4; ++r) {
                int e = min(nb + g * 4 + r, N_EDGES - 1);
                srn[r] = ei[e];
                trn[r] = ei[N_EDGES + e];
            }
        }

        // (5) GEMM1 from LDS (lgkmcnt only)
        v4f acc[8];
        #pragma unroll
        for (int jt = 0; jt < 8; ++jt) {
            int row = 8 * c + jt;
            v4f a4 = (v4f){0.f, 0.f, 0.f, 0.f};
            #pragma unroll
            for (int kc = 0; kc < 4; ++kc) {
                v8bf bb = *(const v8bf*)&v3_s[row][8 * ((g + 4 * kc) ^ (c & 7))];
                a4 = __builtin_amdgcn_mfma_f32_16x16x32_bf16(afrag[kc], bb, a4, 0, 0, 0);
            }
            acc[jt] = a4;
        }

        // (6) epilogue with gathers[T] (a full iteration in flight)
        #pragma unroll
        for (int r = 0; r < 4; ++r) {
            int el = w * 16 + g * 4 + r;
            v8bf o;
            #pragma unroll
            for (int jt = 0; jt < 8; ++jt) {
                float v = acc[jt][r] + (float)qs[r][jt] + (float)qt[r][jt] + b1r[jt];
                o[jt] = (__bf16)gelu_fast(v);
            }
            *(v8bf*)&hc_s[el][8 * (c ^ (el & 7))] = o;
        }

        // (7) GEMM2 + store (hc round-trip wave-local)
        v4f acc2 = (v4f){0.f, 0.f, 0.f, 0.f};
        int arow = w * 16 + c;
        #pragma unroll
        for (int kc = 0; kc < 4; ++kc) {
            int ch = g + 4 * kc;
            v8bf aa = *(const v8bf*)&hc_s[arow][8 * (ch ^ (c & 7))];
            acc2 = __builtin_amdgcn_mfma_f32_16x16x32_bf16(aa, w2frag[kc], acc2, 0, 0, 0);
        }
        #pragma unroll
        for (int r = 0; r < 4; ++r) {
            int e = e_base + g * 4 + r;
            if (e < N_EDGES) out[(size_t)e * 16 + c] = acc2[r] + b2c;
        }

        // (8) rotate
        #pragma unroll
        for (int r = 0; r < 4; ++r) { qs[r] = qsn[r]; qt[r] = qtn[r]; }
        tile = nxt;
    }
}

// ---------------------------------------------------------------------------
extern "C" void kernel_launch(void* const* d_in, const int* in_sizes, int n_in,
                              void* d_out, int out_size, void* d_ws, size_t ws_size,
                              hipStream_t stream) {
    const float* nf   = (const float*)d_in[0];
    const float* ef   = (const float*)d_in[1];
    const int*   ei   = (const int*)d_in[2];
    const int*   lab  = (const int*)d_in[3];
    const float* rel  = (const float*)d_in[4];
    const float* msgW = (const float*)d_in[5];
    const float* msgb = (const float*)d_in[6];
    const float* wih  = (const float*)d_in[7];
    const float* whh  = (const float*)d_in[8];
    const float* bih  = (const float*)d_in[9];
    const float* bhh  = (const float*)d_in[10];
    const float* W1   = (const float*)d_in[11];
    const float* b1   = (const float*)d_in[12];
    const float* W2   = (const float*)d_in[13];
    const float* b2   = (const float*)d_in[14];
    float* out = (float*)d_out;

    char* ws = (char*)d_ws;
    __bf16* WB      = (__bf16*)(ws);                  // 364.5 KB
    __bf16* RPB     = (__bf16*)(ws + 524288);         // 16 KB
    int*    offsets = (int*)(ws + 1048576);           // 200 KB (N+1)
    int*    counts  = (int*)(ws + 1310720);           // 200 KB
    int*    cursor  = (int*)(ws + 1572864);           // 200 KB
    int*    elist   = (int*)(ws + 1835008);           // 2 MB
    __bf16* PSTB    = (__bf16*)(ws + 4194304);        // 25.6 MB
    __bf16* AGG     = (__bf16*)(ws + 33554432);       // 12.8 MB
    __bf16* QSTB    = PSTB;                           // reuse after k_agg

    __bf16* WP1 = WB;
    __bf16* WQ1 = WB + 32768;
    __bf16* V3  = WB + 65536;
    __bf16* W2B = WB + 81920;
    __bf16* WIH = WB + 83968;
    __bf16* WHH = WB + 133120;

    int nblk = (N_NODES + 63) / 64;
    int eblk = (N_EDGES + 255) / 256;

    k_zero<<<(N_NODES + 255) / 256, 256, 0, stream>>>(counts);
    k_pre<<<744 + eblk, 256, 0, stream>>>(msgW, W1, W2, wih, whh, WB,
                                          rel, msgb, RPB, ei, counts);
    k_proj2_f32<<<nblk, 256, 0, stream>>>(nf, WP1, PSTB);
    k_scan<<<1, 1024, 0, stream>>>(counts, offsets, cursor);
    k_scatter<<<eblk, 256, 0, stream>>>(ei, cursor, elist);
    k_agg<<<(N_NODES + 3) / 4, 256, 0, stream>>>(PSTB, RPB, ei, lab, offsets, elist, AGG);
    k_gru_fused<<<nblk, 256, 0, stream>>>(AGG, nf, WIH, WHH, bih, bhh, WQ1, QSTB);
    k_cls_mfma<<<768, 256, 0, stream>>>(ef, QSTB, V3, b1, W2B, b2, ei, out);
}